// Round 1
// baseline (332.045 us; speedup 1.0000x reference)
//
#include <hip/hip_runtime.h>
#include <hip/hip_bf16.h>
#include <stdint.h>

// ---------------------------------------------------------------------------
// SparseLinear: y[B,N] = x[B,M] @ W^T + bias, W given as CSR (row_ids, cols,
// W_val). Strategy: densify W -> bf16 [N,M] in workspace, convert X -> bf16,
// then m97-style 128x128 MFMA bf16 GEMM (16x16x32, global_load_lds width=16).
// B = M = N = 4096, NNZ = 4096*819.
// ---------------------------------------------------------------------------

#define B_DIM 4096
#define M_DIM 4096
#define N_DIM 4096

typedef __attribute__((ext_vector_type(8))) __bf16 bf16x8;
typedef __attribute__((ext_vector_type(4))) float f32x4;

__device__ __forceinline__ unsigned short f32_to_bf16(float f) {
    union { float f; unsigned int u; } v;
    v.f = f;
    unsigned int r = v.u + 0x7FFFu + ((v.u >> 16) & 1u);  // RNE
    return (unsigned short)(r >> 16);
}

__device__ __forceinline__ void load_lds16(const void* g, void* l) {
    __builtin_amdgcn_global_load_lds(
        (const __attribute__((address_space(1))) void*)g,
        (__attribute__((address_space(3))) void*)l,
        16, 0, 0);
}

// ---- prologue kernels ------------------------------------------------------

__global__ void zero_u4(uint4* __restrict__ p, int n16) {
    int i = blockIdx.x * 256 + threadIdx.x;
    if (i < n16) p[i] = make_uint4(0u, 0u, 0u, 0u);
}

__global__ void cvt_x_bf16(const float* __restrict__ x,
                           unsigned short* __restrict__ y, int n4) {
    int i = blockIdx.x * 256 + threadIdx.x;
    if (i >= n4) return;
    const float4 v = ((const float4*)x)[i];
    ushort4 o;
    o.x = f32_to_bf16(v.x);
    o.y = f32_to_bf16(v.y);
    o.z = f32_to_bf16(v.z);
    o.w = f32_to_bf16(v.w);
    ((ushort4*)y)[i] = o;
}

__global__ void scatter_w(const float* __restrict__ wval,
                          const int* __restrict__ row_ids,
                          const int* __restrict__ cols,
                          unsigned short* __restrict__ wb, int nnz) {
    int i = blockIdx.x * 256 + threadIdx.x;
    if (i >= nnz) return;
    int r = row_ids[i];
    int c = cols[i];
    wb[(size_t)r * M_DIM + c] = f32_to_bf16(wval[i]);
}

// ---- main GEMM: C[b,n] = sum_k Xb[b,k]*Wb[n,k] + bias[n] -------------------
// 128x128 block tile, BK=32, 4 waves in 2x2 grid, each wave 64x64 via 4x4
// MFMA 16x16x32 bf16 tiles. Staging via global_load_lds width=16.

#define BK 32

__global__ __launch_bounds__(256) void gemm_bt_bias(
    const unsigned short* __restrict__ Xb,   // [B][M] bf16 bits
    const unsigned short* __restrict__ Wb,   // [N][M] bf16 bits
    const float* __restrict__ bias,          // [N]
    float* __restrict__ out)                 // [B][N]
{
    __shared__ __attribute__((aligned(16))) unsigned short As[128 * BK];
    __shared__ __attribute__((aligned(16))) unsigned short Bs[128 * BK];

    const int tid    = threadIdx.x;
    const int wid    = tid >> 6;      // 0..3
    const int lane   = tid & 63;
    const int wm     = wid & 1;       // wave row (batch dim)
    const int wn     = wid >> 1;      // wave col (N dim)
    const int lane15 = lane & 15;
    const int laneq  = lane >> 4;     // 0..3

    const int bm0 = blockIdx.y * 128;  // batch tile origin
    const int bn0 = blockIdx.x * 128;  // N tile origin

    // staging source pointers: instruction j covers 16 rows; wave wid does
    // instructions {wid, wid+4}. lane i -> row = inst*16 + (i>>2),
    // k-offset = (i&3)*8  (16 bytes = 8 bf16 per lane).
    const int srow = (lane >> 2);
    const int skof = (lane & 3) * 8;

    const unsigned short* aSrc0 =
        Xb + (size_t)(bm0 + wid * 16 + srow) * M_DIM + skof;
    const unsigned short* aSrc1 = aSrc0 + (size_t)64 * M_DIM;
    const unsigned short* bSrc0 =
        Wb + (size_t)(bn0 + wid * 16 + srow) * M_DIM + skof;
    const unsigned short* bSrc1 = bSrc0 + (size_t)64 * M_DIM;

    // wave-uniform LDS destinations (lane scatter = base + lane*16B)
    unsigned short* aDst0 = As + wid * 512;        // inst wid
    unsigned short* aDst1 = As + (wid + 4) * 512;  // inst wid+4
    unsigned short* bDst0 = Bs + wid * 512;
    unsigned short* bDst1 = Bs + (wid + 4) * 512;

    f32x4 acc[4][4];
#pragma unroll
    for (int i = 0; i < 4; ++i)
#pragma unroll
        for (int j = 0; j < 4; ++j) acc[i][j] = (f32x4)0.0f;

    // LDS fragment addresses (fixed across K loop)
    const unsigned short* aFragP[4];
    const unsigned short* bFragP[4];
#pragma unroll
    for (int t = 0; t < 4; ++t) {
        aFragP[t] = As + (wm * 64 + t * 16 + lane15) * BK + laneq * 8;
        bFragP[t] = Bs + (wn * 64 + t * 16 + lane15) * BK + laneq * 8;
    }

    for (int kt = 0; kt < M_DIM; kt += BK) {
        load_lds16(aSrc0 + kt, aDst0);
        load_lds16(aSrc1 + kt, aDst1);
        load_lds16(bSrc0 + kt, bDst0);
        load_lds16(bSrc1 + kt, bDst1);
        __syncthreads();

        bf16x8 af[4], bf[4];
#pragma unroll
        for (int t = 0; t < 4; ++t) {
            af[t] = *((const bf16x8*)aFragP[t]);
            bf[t] = *((const bf16x8*)bFragP[t]);
        }
#pragma unroll
        for (int mt = 0; mt < 4; ++mt)
#pragma unroll
            for (int nt = 0; nt < 4; ++nt)
                acc[mt][nt] = __builtin_amdgcn_mfma_f32_16x16x32_bf16(
                    af[mt], bf[nt], acc[mt][nt], 0, 0, 0);
        __syncthreads();
    }

    // epilogue: D element r of acc[mt][nt] -> row = quad*4+r, col = lane&15
#pragma unroll
    for (int nt = 0; nt < 4; ++nt) {
        const int col = bn0 + wn * 64 + nt * 16 + lane15;
        const float bv = bias[col];
#pragma unroll
        for (int mt = 0; mt < 4; ++mt) {
            const int row0 = bm0 + wm * 64 + mt * 16 + laneq * 4;
#pragma unroll
            for (int r = 0; r < 4; ++r) {
                out[(size_t)(row0 + r) * N_DIM + col] = acc[mt][nt][r] + bv;
            }
        }
    }
}

// ---------------------------------------------------------------------------

extern "C" void kernel_launch(void* const* d_in, const int* in_sizes, int n_in,
                              void* d_out, int out_size, void* d_ws, size_t ws_size,
                              hipStream_t stream) {
    const float* x       = (const float*)d_in[0];
    const float* wval    = (const float*)d_in[1];
    const float* bias    = (const float*)d_in[2];
    const int*   row_ids = (const int*)d_in[3];
    const int*   cols    = (const int*)d_in[4];
    float* out = (float*)d_out;

    const int nnz = in_sizes[1];  // 4096*819

    // workspace layout: Wb [N*M bf16] (32 MiB) | Xb [B*M bf16] (32 MiB)
    unsigned short* Wb = (unsigned short*)d_ws;
    unsigned short* Xb = Wb + (size_t)N_DIM * M_DIM;

    // 1) zero dense W (ws is poisoned each call)
    {
        int n16 = (N_DIM * M_DIM * 2) / 16;  // 2,097,152 uint4
        zero_u4<<<dim3((n16 + 255) / 256), dim3(256), 0, stream>>>((uint4*)Wb, n16);
    }
    // 2) scatter CSR values
    scatter_w<<<dim3((nnz + 255) / 256), dim3(256), 0, stream>>>(
        wval, row_ids, cols, Wb, nnz);
    // 3) convert X to bf16
    {
        int n4 = (B_DIM * M_DIM) / 4;
        cvt_x_bf16<<<dim3((n4 + 255) / 256), dim3(256), 0, stream>>>(x, Xb, n4);
    }
    // 4) GEMM + bias
    gemm_bt_bias<<<dim3(N_DIM / 128, B_DIM / 128), dim3(256), 0, stream>>>(
        Xb, Wb, bias, out);
}

// Round 2
// 318.406 us; speedup vs baseline: 1.0428x; 1.0428x over previous
//
#include <hip/hip_runtime.h>
#include <hip/hip_bf16.h>
#include <stdint.h>

// ---------------------------------------------------------------------------
// SparseLinear: y[B,N] = x[B,M] @ W^T + bias, W given as CSR.
// R2: (1) fused densify (zero+scatter in LDS, coalesced row write),
//     (2) XOR-swizzled LDS k-chunk layout to kill 8-way bank conflicts in
//         the MFMA fragment ds_read_b128s while keeping global_load_lds.
// ---------------------------------------------------------------------------

#define B_DIM 4096
#define M_DIM 4096
#define N_DIM 4096
#define NNZ_ROW 819

typedef __attribute__((ext_vector_type(8))) __bf16 bf16x8;
typedef __attribute__((ext_vector_type(4))) float f32x4;

__device__ __forceinline__ unsigned short f32_to_bf16(float f) {
    union { float f; unsigned int u; } v;
    v.f = f;
    unsigned int r = v.u + 0x7FFFu + ((v.u >> 16) & 1u);  // RNE
    return (unsigned short)(r >> 16);
}

__device__ __forceinline__ void load_lds16(const void* g, void* l) {
    __builtin_amdgcn_global_load_lds(
        (const __attribute__((address_space(1))) void*)g,
        (__attribute__((address_space(3))) void*)l,
        16, 0, 0);
}

// ---- prologue 1: densify one W row per block ------------------------------
// CSR structure is fixed: exactly NNZ_ROW sorted unique cols per row,
// row r's entries at [r*NNZ_ROW, (r+1)*NNZ_ROW).
__global__ __launch_bounds__(256) void densify_w(
    const float* __restrict__ wval,
    const int* __restrict__ cols,
    unsigned short* __restrict__ wb) {
    __shared__ __attribute__((aligned(16))) unsigned short row_s[M_DIM];  // 8 KB
    const int row = blockIdx.x;
    const int tid = threadIdx.x;
    uint4* rs4 = (uint4*)row_s;
    rs4[tid]       = make_uint4(0u, 0u, 0u, 0u);
    rs4[tid + 256] = make_uint4(0u, 0u, 0u, 0u);
    __syncthreads();
    const size_t base = (size_t)row * NNZ_ROW;
    for (int j = tid; j < NNZ_ROW; j += 256) {
        const int c = cols[base + j];
        row_s[c] = f32_to_bf16(wval[base + j]);
    }
    __syncthreads();
    uint4* dst = (uint4*)(wb + (size_t)row * M_DIM);
    dst[tid]       = rs4[tid];
    dst[tid + 256] = rs4[tid + 256];
}

// ---- prologue 2: X fp32 -> bf16, 8 elements/thread ------------------------
__global__ __launch_bounds__(256) void cvt_x_bf16(
    const float4* __restrict__ x, uint4* __restrict__ y, int n8) {
    int i = blockIdx.x * 256 + threadIdx.x;
    if (i >= n8) return;
    const float4 a = x[2 * i];
    const float4 b = x[2 * i + 1];
    union { ushort ush[8]; uint4 u4; } o;
    o.ush[0] = f32_to_bf16(a.x); o.ush[1] = f32_to_bf16(a.y);
    o.ush[2] = f32_to_bf16(a.z); o.ush[3] = f32_to_bf16(a.w);
    o.ush[4] = f32_to_bf16(b.x); o.ush[5] = f32_to_bf16(b.y);
    o.ush[6] = f32_to_bf16(b.z); o.ush[7] = f32_to_bf16(b.w);
    y[i] = o.u4;
}

// ---- main GEMM: C[b,n] = sum_k Xb[b,k]*Wb[n,k] + bias[n] -------------------
// 128x128 block tile, BK=32, 4 waves 2x2, each wave 64x64 via 4x4 MFMA
// 16x16x32 bf16. Staging via global_load_lds width=16 with XOR k-chunk
// swizzle: LDS (row, slot) holds global k-chunk slot^((row>>1)&3).

#define BK 32

__global__ __launch_bounds__(256) void gemm_bt_bias(
    const unsigned short* __restrict__ Xb,   // [B][M] bf16 bits
    const unsigned short* __restrict__ Wb,   // [N][M] bf16 bits
    const float* __restrict__ bias,          // [N]
    float* __restrict__ out)                 // [B][N]
{
    __shared__ __attribute__((aligned(16))) unsigned short As[128 * BK];
    __shared__ __attribute__((aligned(16))) unsigned short Bs[128 * BK];

    const int tid    = threadIdx.x;
    const int wid    = tid >> 6;      // 0..3
    const int lane   = tid & 63;
    const int wm     = wid & 1;       // wave row (batch dim)
    const int wn     = wid >> 1;      // wave col (N dim)
    const int lane15 = lane & 15;
    const int laneq  = lane >> 4;     // 0..3

    const int bm0 = blockIdx.y * 128;  // batch tile origin
    const int bn0 = blockIdx.x * 128;  // N tile origin

    // staging: inst j covers rows j*16..j*16+15; lane i -> row j*16 + (i>>2),
    // global k-chunk g = (i&3) ^ ((i>>3)&3)  (XOR swizzle), 8 bf16 per chunk.
    const int srow = (lane >> 2);
    const int skof = ((lane & 3) ^ ((lane >> 3) & 3)) * 8;

    const unsigned short* aSrc0 =
        Xb + (size_t)(bm0 + wid * 16 + srow) * M_DIM + skof;
    const unsigned short* aSrc1 = aSrc0 + (size_t)64 * M_DIM;
    const unsigned short* bSrc0 =
        Wb + (size_t)(bn0 + wid * 16 + srow) * M_DIM + skof;
    const unsigned short* bSrc1 = bSrc0 + (size_t)64 * M_DIM;

    // wave-uniform LDS destinations (lane scatter = base + lane*16B)
    unsigned short* aDst0 = As + wid * 512;
    unsigned short* aDst1 = As + (wid + 4) * 512;
    unsigned short* bDst0 = Bs + wid * 512;
    unsigned short* bDst1 = Bs + (wid + 4) * 512;

    f32x4 acc[4][4];
#pragma unroll
    for (int i = 0; i < 4; ++i)
#pragma unroll
        for (int j = 0; j < 4; ++j) acc[i][j] = (f32x4)0.0f;

    // fragment read: lane wants (row = lane15 + 16t(+64wm), k-chunk = laneq);
    // it lives in LDS slot laneq ^ ((lane15>>1)&3). 16 rows of a quad now
    // span all 8 bank-groups twice -> 2-way (free) instead of 8-way.
    const int slot = (laneq ^ ((lane15 >> 1) & 3)) * 8;
    const unsigned short* aFragP[4];
    const unsigned short* bFragP[4];
#pragma unroll
    for (int t = 0; t < 4; ++t) {
        aFragP[t] = As + (wm * 64 + t * 16 + lane15) * BK + slot;
        bFragP[t] = Bs + (wn * 64 + t * 16 + lane15) * BK + slot;
    }

    for (int kt = 0; kt < M_DIM; kt += BK) {
        load_lds16(aSrc0 + kt, aDst0);
        load_lds16(aSrc1 + kt, aDst1);
        load_lds16(bSrc0 + kt, bDst0);
        load_lds16(bSrc1 + kt, bDst1);
        __syncthreads();

        bf16x8 af[4], bf[4];
#pragma unroll
        for (int t = 0; t < 4; ++t) {
            af[t] = *((const bf16x8*)aFragP[t]);
            bf[t] = *((const bf16x8*)bFragP[t]);
        }
#pragma unroll
        for (int mt = 0; mt < 4; ++mt)
#pragma unroll
            for (int nt = 0; nt < 4; ++nt)
                acc[mt][nt] = __builtin_amdgcn_mfma_f32_16x16x32_bf16(
                    af[mt], bf[nt], acc[mt][nt], 0, 0, 0);
        __syncthreads();
    }

    // epilogue: D element r of acc[mt][nt] -> row = laneq*4+r, col = lane15
#pragma unroll
    for (int nt = 0; nt < 4; ++nt) {
        const int col = bn0 + wn * 64 + nt * 16 + lane15;
        const float bv = bias[col];
#pragma unroll
        for (int mt = 0; mt < 4; ++mt) {
            const int row0 = bm0 + wm * 64 + mt * 16 + laneq * 4;
#pragma unroll
            for (int r = 0; r < 4; ++r) {
                out[(size_t)(row0 + r) * N_DIM + col] = acc[mt][nt][r] + bv;
            }
        }
    }
}

// ---------------------------------------------------------------------------

extern "C" void kernel_launch(void* const* d_in, const int* in_sizes, int n_in,
                              void* d_out, int out_size, void* d_ws, size_t ws_size,
                              hipStream_t stream) {
    const float* x       = (const float*)d_in[0];
    const float* wval    = (const float*)d_in[1];
    const float* bias    = (const float*)d_in[2];
    const int*   cols    = (const int*)d_in[4];
    float* out = (float*)d_out;

    // workspace: Wb [N*M bf16] (32 MiB) | Xb [B*M bf16] (32 MiB)
    unsigned short* Wb = (unsigned short*)d_ws;
    unsigned short* Xb = Wb + (size_t)N_DIM * M_DIM;

    // 1) densify W (fused zero + scatter, coalesced row writes)
    densify_w<<<dim3(N_DIM), dim3(256), 0, stream>>>(wval, cols, Wb);
    // 2) convert X to bf16
    {
        int n8 = (B_DIM * M_DIM) / 8;
        cvt_x_bf16<<<dim3(n8 / 256), dim3(256), 0, stream>>>(
            (const float4*)x, (uint4*)Xb, n8);
    }
    // 3) GEMM + bias
    gemm_bt_bias<<<dim3(N_DIM / 128, B_DIM / 128), dim3(256), 0, stream>>>(
        Xb, Wb, bias, out);
}

// Round 3
// 305.903 us; speedup vs baseline: 1.0855x; 1.0409x over previous
//
#include <hip/hip_runtime.h>
#include <hip/hip_bf16.h>
#include <stdint.h>

// ---------------------------------------------------------------------------
// SparseLinear: y[B,N] = x[B,M] @ W^T + bias, W given as CSR.
// R3: GEMM switched to 32x32x16 bf16 MFMA (2x2 tiles/wave) + double-buffered
//     LDS with prefetch-before-compute, ONE barrier per K-iter. XOR k-chunk
//     swizzle retained (verified conflict-free in R2).
// ---------------------------------------------------------------------------

#define B_DIM 4096
#define M_DIM 4096
#define N_DIM 4096
#define NNZ_ROW 819
#define BK 32

typedef __attribute__((ext_vector_type(8))) __bf16 bf16x8;
typedef __attribute__((ext_vector_type(16))) float f32x16;

__device__ __forceinline__ unsigned short f32_to_bf16(float f) {
    union { float f; unsigned int u; } v;
    v.f = f;
    unsigned int r = v.u + 0x7FFFu + ((v.u >> 16) & 1u);  // RNE
    return (unsigned short)(r >> 16);
}

__device__ __forceinline__ void load_lds16(const void* g, void* l) {
    __builtin_amdgcn_global_load_lds(
        (const __attribute__((address_space(1))) void*)g,
        (__attribute__((address_space(3))) void*)l,
        16, 0, 0);
}

// ---- prologue 1: densify one W row per block (verified R2) ----------------
__global__ __launch_bounds__(256) void densify_w(
    const float* __restrict__ wval,
    const int* __restrict__ cols,
    unsigned short* __restrict__ wb) {
    __shared__ __attribute__((aligned(16))) unsigned short row_s[M_DIM];  // 8 KB
    const int row = blockIdx.x;
    const int tid = threadIdx.x;
    uint4* rs4 = (uint4*)row_s;
    rs4[tid]       = make_uint4(0u, 0u, 0u, 0u);
    rs4[tid + 256] = make_uint4(0u, 0u, 0u, 0u);
    __syncthreads();
    const size_t base = (size_t)row * NNZ_ROW;
    for (int j = tid; j < NNZ_ROW; j += 256) {
        const int c = cols[base + j];
        row_s[c] = f32_to_bf16(wval[base + j]);
    }
    __syncthreads();
    uint4* dst = (uint4*)(wb + (size_t)row * M_DIM);
    dst[tid]       = rs4[tid];
    dst[tid + 256] = rs4[tid + 256];
}

// ---- prologue 2: X fp32 -> bf16 -------------------------------------------
__global__ __launch_bounds__(256) void cvt_x_bf16(
    const float4* __restrict__ x, uint4* __restrict__ y, int n8) {
    int i = blockIdx.x * 256 + threadIdx.x;
    if (i >= n8) return;
    const float4 a = x[2 * i];
    const float4 b = x[2 * i + 1];
    union { ushort ush[8]; uint4 u4; } o;
    o.ush[0] = f32_to_bf16(a.x); o.ush[1] = f32_to_bf16(a.y);
    o.ush[2] = f32_to_bf16(a.z); o.ush[3] = f32_to_bf16(a.w);
    o.ush[4] = f32_to_bf16(b.x); o.ush[5] = f32_to_bf16(b.y);
    o.ush[6] = f32_to_bf16(b.z); o.ush[7] = f32_to_bf16(b.w);
    y[i] = o.u4;
}

// ---- main GEMM: C[b,n] = sum_k Xb[b,k]*Wb[n,k] + bias[n] -------------------
// 128x128 block tile, BK=32, 4 waves 2x2, wave tile 64x64 = 2x2 of 32x32x16
// MFMA. Double-buffered LDS (8 KB per matrix per buf = 32 KB total).
// A operand: lane holds A[m=lane&31][k=8*(lane>>5)+j] (4 VGPR).
// C/D: col=lane&31, row=(reg&3)+8*(reg>>2)+4*(lane>>5)  [m74/m101].

__global__ __launch_bounds__(256, 4) void gemm_bt_bias(
    const unsigned short* __restrict__ Xb,   // [B][M] bf16 bits
    const unsigned short* __restrict__ Wb,   // [N][M] bf16 bits
    const float* __restrict__ bias,          // [N]
    float* __restrict__ out)                 // [B][N]
{
    __shared__ __attribute__((aligned(16))) unsigned short As[2 * 128 * BK];
    __shared__ __attribute__((aligned(16))) unsigned short Bs[2 * 128 * BK];

    const int tid    = threadIdx.x;
    const int wid    = tid >> 6;      // 0..3
    const int lane   = tid & 63;
    const int wm     = wid & 1;       // wave row (batch dim)
    const int wn     = wid >> 1;      // wave col (N dim)
    const int m31    = lane & 31;     // row within 32-tile (A: batch, B: n)
    const int chalf  = lane >> 5;     // k-half selector

    const int bm0 = blockIdx.y * 128;
    const int bn0 = blockIdx.x * 128;

    // ---- staging (same pattern as R2, verified conflict-free) ----
    // inst j covers rows j*16..j*16+15; lane i -> row j*16+(i>>2),
    // global k-chunk (i&3)^((i>>3)&3), so LDS(row r, slot t) holds global
    // chunk t^((r>>1)&3).
    const int srow = (lane >> 2);
    const int skof = ((lane & 3) ^ ((lane >> 3) & 3)) * 8;

    const unsigned short* aSrc0 =
        Xb + (size_t)(bm0 + wid * 16 + srow) * M_DIM + skof;
    const unsigned short* aSrc1 = aSrc0 + (size_t)64 * M_DIM;
    const unsigned short* bSrc0 =
        Wb + (size_t)(bn0 + wid * 16 + srow) * M_DIM + skof;
    const unsigned short* bSrc1 = bSrc0 + (size_t)64 * M_DIM;

    const int dOff0 = wid * 512;        // inst wid
    const int dOff1 = (wid + 4) * 512;  // inst wid+4

    // ---- fragment read offsets (element units, per k-step s) ----
    // lane wants (row R, chunk c = s*2 + chalf); stored at slot c^((R>>1)&3);
    // base rows are multiples of 32 so (R>>1)&3 = (m31>>1)&3.
    const int q2 = (m31 >> 1) & 3;
    int aOff[2][2], bOff[2][2];  // [mt|nt][s]
#pragma unroll
    for (int t = 0; t < 2; ++t)
#pragma unroll
        for (int s = 0; s < 2; ++s) {
            const int slot = ((s * 2 + chalf) ^ q2) * 8;
            aOff[t][s] = (wm * 64 + t * 32 + m31) * BK + slot;
            bOff[t][s] = (wn * 64 + t * 32 + m31) * BK + slot;
        }

    f32x16 acc[2][2];
#pragma unroll
    for (int i = 0; i < 2; ++i)
#pragma unroll
        for (int j = 0; j < 2; ++j) acc[i][j] = (f32x16)0.0f;

    // ---- prologue stage of chunk 0 into buf 0 ----
    load_lds16(aSrc0, As + dOff0);
    load_lds16(aSrc1, As + dOff1);
    load_lds16(bSrc0, Bs + dOff0);
    load_lds16(bSrc1, Bs + dOff1);
    __syncthreads();

    int buf = 0;
    for (int kt = 0; kt < M_DIM; kt += BK) {
        const int nbase = (buf ^ 1) * (128 * BK);
        if (kt + BK < M_DIM) {
            // prefetch next chunk into the other buffer (no wait needed now)
            load_lds16(aSrc0 + kt + BK, As + nbase + dOff0);
            load_lds16(aSrc1 + kt + BK, As + nbase + dOff1);
            load_lds16(bSrc0 + kt + BK, Bs + nbase + dOff0);
            load_lds16(bSrc1 + kt + BK, Bs + nbase + dOff1);
        }
        const int cbase = buf * (128 * BK);
#pragma unroll
        for (int s = 0; s < 2; ++s) {
            bf16x8 af[2], bf[2];
#pragma unroll
            for (int t = 0; t < 2; ++t) {
                af[t] = *((const bf16x8*)(As + cbase + aOff[t][s]));
                bf[t] = *((const bf16x8*)(Bs + cbase + bOff[t][s]));
            }
#pragma unroll
            for (int mt = 0; mt < 2; ++mt)
#pragma unroll
                for (int nt = 0; nt < 2; ++nt)
                    acc[mt][nt] = __builtin_amdgcn_mfma_f32_32x32x16_bf16(
                        af[mt], bf[nt], acc[mt][nt], 0, 0, 0);
        }
        // one barrier per iter: (a) everyone done reading buf before it is
        // overwritten next iter, (b) implicit vmcnt(0) drains the prefetch
        // before anyone reads the other buffer.
        __syncthreads();
        buf ^= 1;
    }

    // ---- epilogue: C/D row=(reg&3)+8*(reg>>2)+4*chalf, col=m31 ----
#pragma unroll
    for (int nt = 0; nt < 2; ++nt) {
        const int col = bn0 + wn * 64 + nt * 32 + m31;
        const float bv = bias[col];
#pragma unroll
        for (int mt = 0; mt < 2; ++mt) {
            const int row_base = bm0 + wm * 64 + mt * 32 + 4 * chalf;
#pragma unroll
            for (int r = 0; r < 16; ++r) {
                const int row = row_base + (r & 3) + 8 * (r >> 2);
                out[(size_t)row * N_DIM + col] = acc[mt][nt][r] + bv;
            }
        }
    }
}

// ---------------------------------------------------------------------------

extern "C" void kernel_launch(void* const* d_in, const int* in_sizes, int n_in,
                              void* d_out, int out_size, void* d_ws, size_t ws_size,
                              hipStream_t stream) {
    const float* x       = (const float*)d_in[0];
    const float* wval    = (const float*)d_in[1];
    const float* bias    = (const float*)d_in[2];
    const int*   cols    = (const int*)d_in[4];
    float* out = (float*)d_out;

    // workspace: Wb [N*M bf16] (32 MiB) | Xb [B*M bf16] (32 MiB)
    unsigned short* Wb = (unsigned short*)d_ws;
    unsigned short* Xb = Wb + (size_t)N_DIM * M_DIM;

    densify_w<<<dim3(N_DIM), dim3(256), 0, stream>>>(wval, cols, Wb);
    {
        int n8 = (B_DIM * M_DIM) / 8;
        cvt_x_bf16<<<dim3(n8 / 256), dim3(256), 0, stream>>>(
            (const float4*)x, (uint4*)Xb, n8);
    }
    gemm_bt_bias<<<dim3(N_DIM / 128, B_DIM / 128), dim3(256), 0, stream>>>(
        Xb, Wb, bias, out);
}

// Round 4
// 302.537 us; speedup vs baseline: 1.0975x; 1.0111x over previous
//
#include <hip/hip_runtime.h>
#include <hip/hip_bf16.h>
#include <stdint.h>

// ---------------------------------------------------------------------------
// SparseLinear: y[B,N] = x[B,M] @ W^T + bias, W given as CSR.
// R4: combine the two empirically-proven wins:
//   - R2's 16x16x32 MFMA fragment-read pattern (measured ZERO bank conflicts)
//   - R3's double-buffered single-barrier K-loop (measured +8 us)
// R3's 32x32 fragment reads re-introduced R1-magnitude conflicts; reverted.
// ---------------------------------------------------------------------------

#define B_DIM 4096
#define M_DIM 4096
#define N_DIM 4096
#define NNZ_ROW 819
#define BK 32

typedef __attribute__((ext_vector_type(8))) __bf16 bf16x8;
typedef __attribute__((ext_vector_type(4))) float f32x4;

__device__ __forceinline__ unsigned short f32_to_bf16(float f) {
    union { float f; unsigned int u; } v;
    v.f = f;
    unsigned int r = v.u + 0x7FFFu + ((v.u >> 16) & 1u);  // RNE
    return (unsigned short)(r >> 16);
}

__device__ __forceinline__ void load_lds16(const void* g, void* l) {
    __builtin_amdgcn_global_load_lds(
        (const __attribute__((address_space(1))) void*)g,
        (__attribute__((address_space(3))) void*)l,
        16, 0, 0);
}

// ---- prologue 1: densify one W row per block (verified R2) ----------------
__global__ __launch_bounds__(256) void densify_w(
    const float* __restrict__ wval,
    const int* __restrict__ cols,
    unsigned short* __restrict__ wb) {
    __shared__ __attribute__((aligned(16))) unsigned short row_s[M_DIM];  // 8 KB
    const int row = blockIdx.x;
    const int tid = threadIdx.x;
    uint4* rs4 = (uint4*)row_s;
    rs4[tid]       = make_uint4(0u, 0u, 0u, 0u);
    rs4[tid + 256] = make_uint4(0u, 0u, 0u, 0u);
    __syncthreads();
    const size_t base = (size_t)row * NNZ_ROW;
    for (int j = tid; j < NNZ_ROW; j += 256) {
        const int c = cols[base + j];
        row_s[c] = f32_to_bf16(wval[base + j]);
    }
    __syncthreads();
    uint4* dst = (uint4*)(wb + (size_t)row * M_DIM);
    dst[tid]       = rs4[tid];
    dst[tid + 256] = rs4[tid + 256];
}

// ---- prologue 2: X fp32 -> bf16 -------------------------------------------
__global__ __launch_bounds__(256) void cvt_x_bf16(
    const float4* __restrict__ x, uint4* __restrict__ y, int n8) {
    int i = blockIdx.x * 256 + threadIdx.x;
    if (i >= n8) return;
    const float4 a = x[2 * i];
    const float4 b = x[2 * i + 1];
    union { ushort ush[8]; uint4 u4; } o;
    o.ush[0] = f32_to_bf16(a.x); o.ush[1] = f32_to_bf16(a.y);
    o.ush[2] = f32_to_bf16(a.z); o.ush[3] = f32_to_bf16(a.w);
    o.ush[4] = f32_to_bf16(b.x); o.ush[5] = f32_to_bf16(b.y);
    o.ush[6] = f32_to_bf16(b.z); o.ush[7] = f32_to_bf16(b.w);
    y[i] = o.u4;
}

// ---- main GEMM: C[b,n] = sum_k Xb[b,k]*Wb[n,k] + bias[n] -------------------
// 128x128 block tile, BK=32, 4 waves 2x2, wave tile 64x64 = 4x4 of 16x16x32
// MFMA (R2's proven conflict-free read pattern). Double-buffered LDS,
// one barrier per K-iter (prefetch issued before compute; the implicit
// vmcnt(0) drain at the barrier guarantees landing before the buffer swap).

__global__ __launch_bounds__(256, 4) void gemm_bt_bias(
    const unsigned short* __restrict__ Xb,   // [B][M] bf16 bits
    const unsigned short* __restrict__ Wb,   // [N][M] bf16 bits
    const float* __restrict__ bias,          // [N]
    float* __restrict__ out)                 // [B][N]
{
    __shared__ __attribute__((aligned(16))) unsigned short As[2 * 128 * BK];
    __shared__ __attribute__((aligned(16))) unsigned short Bs[2 * 128 * BK];

    const int tid    = threadIdx.x;
    const int wid    = tid >> 6;      // 0..3
    const int lane   = tid & 63;
    const int wm     = wid & 1;       // wave row (batch dim)
    const int wn     = wid >> 1;      // wave col (N dim)
    const int lane15 = lane & 15;
    const int laneq  = lane >> 4;     // 0..3

    const int bm0 = blockIdx.y * 128;
    const int bn0 = blockIdx.x * 128;

    // ---- staging (R2 pattern): inst j covers rows j*16..j*16+15;
    // lane i -> row j*16+(i>>2), global k-chunk (i&3)^((i>>3)&3), so
    // LDS(row r, slot t) holds global chunk t^((r>>1)&3).
    const int srow = (lane >> 2);
    const int skof = ((lane & 3) ^ ((lane >> 3) & 3)) * 8;

    const unsigned short* aSrc0 =
        Xb + (size_t)(bm0 + wid * 16 + srow) * M_DIM + skof;
    const unsigned short* aSrc1 = aSrc0 + (size_t)64 * M_DIM;
    const unsigned short* bSrc0 =
        Wb + (size_t)(bn0 + wid * 16 + srow) * M_DIM + skof;
    const unsigned short* bSrc1 = bSrc0 + (size_t)64 * M_DIM;

    const int dOff0 = wid * 512;        // inst wid
    const int dOff1 = (wid + 4) * 512;  // inst wid+4

    // ---- fragment read offsets (R2's measured-conflict-free pattern) ----
    // lane wants (row = lane15 + 16t + 64wm, chunk = laneq); stored at slot
    // laneq ^ ((lane15>>1)&3).
    const int slot = (laneq ^ ((lane15 >> 1) & 3)) * 8;
    int aOff[4], bOff[4];
#pragma unroll
    for (int t = 0; t < 4; ++t) {
        aOff[t] = (wm * 64 + t * 16 + lane15) * BK + slot;
        bOff[t] = (wn * 64 + t * 16 + lane15) * BK + slot;
    }

    f32x4 acc[4][4];
#pragma unroll
    for (int i = 0; i < 4; ++i)
#pragma unroll
        for (int j = 0; j < 4; ++j) acc[i][j] = (f32x4)0.0f;

    // ---- prologue stage of chunk 0 into buf 0 ----
    load_lds16(aSrc0, As + dOff0);
    load_lds16(aSrc1, As + dOff1);
    load_lds16(bSrc0, Bs + dOff0);
    load_lds16(bSrc1, Bs + dOff1);
    __syncthreads();

    int buf = 0;
    for (int kt = 0; kt < M_DIM; kt += BK) {
        const int nbase = (buf ^ 1) * (128 * BK);
        if (kt + BK < M_DIM) {
            // prefetch next chunk into the other buffer; latency overlaps
            // the MFMA/ds_read section below.
            load_lds16(aSrc0 + kt + BK, As + nbase + dOff0);
            load_lds16(aSrc1 + kt + BK, As + nbase + dOff1);
            load_lds16(bSrc0 + kt + BK, Bs + nbase + dOff0);
            load_lds16(bSrc1 + kt + BK, Bs + nbase + dOff1);
        }
        const int cbase = buf * (128 * BK);

        bf16x8 af[4], bf[4];
#pragma unroll
        for (int t = 0; t < 4; ++t) {
            af[t] = *((const bf16x8*)(As + cbase + aOff[t]));
            bf[t] = *((const bf16x8*)(Bs + cbase + bOff[t]));
        }
#pragma unroll
        for (int mt = 0; mt < 4; ++mt)
#pragma unroll
            for (int nt = 0; nt < 4; ++nt)
                acc[mt][nt] = __builtin_amdgcn_mfma_f32_16x16x32_bf16(
                    af[mt], bf[nt], acc[mt][nt], 0, 0, 0);

        // one barrier: everyone done reading buf, and the implicit
        // vmcnt(0) drain lands the prefetch before the swap.
        __syncthreads();
        buf ^= 1;
    }

    // ---- epilogue: D elem r of acc[mt][nt] -> row = laneq*4+r, col = lane15
#pragma unroll
    for (int nt = 0; nt < 4; ++nt) {
        const int col = bn0 + wn * 64 + nt * 16 + lane15;
        const float bv = bias[col];
#pragma unroll
        for (int mt = 0; mt < 4; ++mt) {
            const int row0 = bm0 + wm * 64 + mt * 16 + laneq * 4;
#pragma unroll
            for (int r = 0; r < 4; ++r) {
                out[(size_t)(row0 + r) * N_DIM + col] = acc[mt][nt][r] + bv;
            }
        }
    }
}

// ---------------------------------------------------------------------------

extern "C" void kernel_launch(void* const* d_in, const int* in_sizes, int n_in,
                              void* d_out, int out_size, void* d_ws, size_t ws_size,
                              hipStream_t stream) {
    const float* x       = (const float*)d_in[0];
    const float* wval    = (const float*)d_in[1];
    const float* bias    = (const float*)d_in[2];
    const int*   cols    = (const int*)d_in[4];
    float* out = (float*)d_out;

    // workspace: Wb [N*M bf16] (32 MiB) | Xb [B*M bf16] (32 MiB)
    unsigned short* Wb = (unsigned short*)d_ws;
    unsigned short* Xb = Wb + (size_t)N_DIM * M_DIM;

    densify_w<<<dim3(N_DIM), dim3(256), 0, stream>>>(wval, cols, Wb);
    {
        int n8 = (B_DIM * M_DIM) / 8;
        cvt_x_bf16<<<dim3(n8 / 256), dim3(256), 0, stream>>>(
            (const float4*)x, (uint4*)Xb, n8);
    }
    gemm_bt_bias<<<dim3(N_DIM / 128, B_DIM / 128), dim3(256), 0, stream>>>(
        Xb, Wb, bias, out);
}